// Round 1
// baseline (937.475 us; speedup 1.0000x reference)
//
#include <hip/hip_runtime.h>
#include <math.h>

// NonlocalWeightedAverage, fused flash-style, fp32 VALU baseline.
//
// corr[n,m] = sum_{dy,dx in 3x3} P((ny+dy,nx+dx),(my+dy,mx+dx)),
// P = per-pixel channel gram. Per workgroup (b, ny): loop over key rows my,
// compute 3 row-grams (64x64x64 matmul each) into LDS, assemble corr 4x4
// blocks per thread, online softmax, weighted sum with x_lab.

#define BATCH 4
#define CH    64
#define HH    64
#define WW    64
#define NPIX  (HH * WW)
#define SCALE 10.0f   // 1 / ALPHA

__global__ __launch_bounds__(256) void nlwa_kernel(
    const float* __restrict__ x_lab,     // [4, 3, 64, 64]
    const float* __restrict__ feature,   // [4, 64, 64, 64]
    float* __restrict__ out)             // [4, 3, 64, 64]
{
    // 16384 floats = 64 KB exactly.
    //   smem[0 .. 12288)  : qf[3][64][64]  (rows ny-1..ny+1, [dyi][c][x])
    //   smem[12288..16384): gram g[64][64] ([a][b]), one dy at a time
    //   smem[0 .. 5120)   : reused at the end as softmax combine scratch
    __shared__ __align__(16) float smem[16384];
    float* const gmem = smem + 12288;

    const int tid = threadIdx.x;
    const int b   = blockIdx.x >> 6;
    const int ny  = blockIdx.x & 63;

    const int bg = tid & 15;     // key group    -> mx base
    const int ag = tid >> 4;     // query group  -> nx base
    const int a0 = ag << 2;
    const int b0 = bg << 2;

    const float* const fbase = feature + (size_t)b * (CH * NPIX);

    // ---- stage query feature rows ny-1..ny+1 into LDS (zeros for OOB) ----
    for (int idx = tid; idx < 3 * CH * WW; idx += 256) {
        const int dyi = idx >> 12;
        const int rem = idx & 4095;
        const int c   = rem >> 6;
        const int x   = rem & 63;
        const int row = ny + dyi - 1;
        float v = 0.0f;
        if (row >= 0 && row < HH) v = fbase[((size_t)c * HH + row) * WW + x];
        smem[idx] = v;
    }
    __syncthreads();

    // ---- online softmax state: 4 queries (a0..a0+3) per thread ----
    float m_[4], l_[4], A_[4][3];
#pragma unroll
    for (int i = 0; i < 4; ++i) {
        m_[i] = -3.0e38f; l_[i] = 0.0f;
        A_[i][0] = 0.0f; A_[i][1] = 0.0f; A_[i][2] = 0.0f;
    }

    for (int my = 0; my < HH; ++my) {
        float corr[4][4];
#pragma unroll
        for (int i = 0; i < 4; ++i)
#pragma unroll
            for (int j = 0; j < 4; ++j) corr[i][j] = 0.0f;

        for (int dyi = 0; dyi < 3; ++dyi) {
            const int qrow = ny + dyi - 1;
            const int krow = my + dyi - 1;
            const bool vdy = (qrow >= 0) && (qrow < HH) &&
                             (krow >= 0) && (krow < HH);   // uniform across block
            if (vdy) {
                // gram: g[a][b] = sum_c qf[dyi][c][a] * f[c][krow][b]
                float acc[4][4];
#pragma unroll
                for (int i = 0; i < 4; ++i)
#pragma unroll
                    for (int j = 0; j < 4; ++j) acc[i][j] = 0.0f;

                const float* qptr = smem + dyi * 4096 + a0;             // LDS
                const float* kptr = fbase + (size_t)krow * WW + b0;     // global
#pragma unroll 4
                for (int c = 0; c < CH; ++c) {
                    const float4 q4 = *(const float4*)(qptr + c * 64);
                    const float4 k4 = *(const float4*)(kptr + (size_t)c * NPIX);
                    const float qa[4] = {q4.x, q4.y, q4.z, q4.w};
                    const float kb[4] = {k4.x, k4.y, k4.z, k4.w};
#pragma unroll
                    for (int i = 0; i < 4; ++i)
#pragma unroll
                        for (int j = 0; j < 4; ++j)
                            acc[i][j] = fmaf(qa[i], kb[j], acc[i][j]);
                }
#pragma unroll
                for (int i = 0; i < 4; ++i) {
                    float4 st = make_float4(acc[i][0], acc[i][1], acc[i][2], acc[i][3]);
                    *(float4*)(gmem + (a0 + i) * 64 + b0) = st;
                }
            }
            __syncthreads();
            if (vdy) {
                // corr[i][j] += sum_dx g[a0+i+dx][b0+j+dx] (valid dx only)
#pragma unroll
                for (int i = 0; i < 4; ++i) {
#pragma unroll
                    for (int dx = -1; dx <= 1; ++dx) {
                        const int a2 = a0 + i + dx;
                        if (a2 < 0 || a2 >= WW) continue;
                        const float* grow = gmem + a2 * 64;
#pragma unroll
                        for (int j = 0; j < 4; ++j) {
                            const int b2 = b0 + j + dx;
                            if (b2 >= 0 && b2 < WW) corr[i][j] += grow[b2];
                        }
                    }
                }
            }
            __syncthreads();
        }

        // ---- online softmax update with this key row ----
        float xv[3][4];
        const float* xb = x_lab + (size_t)b * 3 * NPIX + (size_t)my * WW + b0;
#pragma unroll
        for (int ch = 0; ch < 3; ++ch) {
            const float4 x4 = *(const float4*)(xb + (size_t)ch * NPIX);
            xv[ch][0] = x4.x; xv[ch][1] = x4.y; xv[ch][2] = x4.z; xv[ch][3] = x4.w;
        }
#pragma unroll
        for (int i = 0; i < 4; ++i) {
            const float s0 = corr[i][0] * SCALE;
            const float s1 = corr[i][1] * SCALE;
            const float s2 = corr[i][2] * SCALE;
            const float s3 = corr[i][3] * SCALE;
            const float smax = fmaxf(fmaxf(s0, s1), fmaxf(s2, s3));
            const float mnew = fmaxf(m_[i], smax);
            const float sc = __expf(m_[i] - mnew);
            const float e0 = __expf(s0 - mnew);
            const float e1 = __expf(s1 - mnew);
            const float e2 = __expf(s2 - mnew);
            const float e3 = __expf(s3 - mnew);
            l_[i] = l_[i] * sc + (e0 + e1 + e2 + e3);
#pragma unroll
            for (int ch = 0; ch < 3; ++ch) {
                A_[i][ch] = A_[i][ch] * sc
                          + e0 * xv[ch][0] + e1 * xv[ch][1]
                          + e2 * xv[ch][2] + e3 * xv[ch][3];
            }
            m_[i] = mnew;
        }
    }

    // ---- combine the 16 key-group partials per query ----
    __syncthreads();   // qf region dead; reuse smem[0..5120) as scratch
#pragma unroll
    for (int i = 0; i < 4; ++i) {
        const int q = a0 + i;
        float* p = smem + (q * 16 + bg) * 5;
        p[0] = m_[i]; p[1] = l_[i];
        p[2] = A_[i][0]; p[3] = A_[i][1]; p[4] = A_[i][2];
    }
    __syncthreads();
    if (tid < 64) {
        const int q = tid;
        float mstar = -3.0e38f;
        for (int g = 0; g < 16; ++g)
            mstar = fmaxf(mstar, smem[(q * 16 + g) * 5]);
        float lsum = 0.0f, c0 = 0.0f, c1 = 0.0f, c2 = 0.0f;
        for (int g = 0; g < 16; ++g) {
            const float* p = smem + (q * 16 + g) * 5;
            const float w = __expf(p[0] - mstar);
            lsum += w * p[1];
            c0 += w * p[2]; c1 += w * p[3]; c2 += w * p[4];
        }
        const float inv = 1.0f / lsum;
        const size_t o = (size_t)b * 3 * NPIX + (size_t)ny * WW + q;
        out[o]            = c0 * inv;
        out[o + NPIX]     = c1 * inv;
        out[o + 2 * NPIX] = c2 * inv;
    }
}

extern "C" void kernel_launch(void* const* d_in, const int* in_sizes, int n_in,
                              void* d_out, int out_size, void* d_ws, size_t ws_size,
                              hipStream_t stream) {
    const float* x_lab   = (const float*)d_in[0];
    const float* feature = (const float*)d_in[1];
    float* out = (float*)d_out;
    nlwa_kernel<<<dim3(BATCH * HH), dim3(256), 0, stream>>>(x_lab, feature, out);
}

// Round 2
// 138.413 us; speedup vs baseline: 6.7730x; 6.7730x over previous
//
#include <hip/hip_runtime.h>
#include <math.h>

// NonlocalWeightedAverage via 9-shift bf16 MFMA flash attention.
// corr(row ny, row my) = sum_{(dy,dx) in 3x3} Qshift^T Kshift, K=64 each.
// Shifts = +/-16B offsets into zero-padded LDS rows in fragment order.

#define HH 64
#define WW 64
#define CH 64
#define NPIX 4096
#define SCALE 10.0f
#define ROWCH 528              // 16B chunks per padded row: 8 kchunks * 66 xslots
#define ROWB  (ROWCH * 16)     // 8448 bytes

typedef __attribute__((ext_vector_type(8))) short bf16x8;
typedef __attribute__((ext_vector_type(4))) float f32x4;

// ---------------- pre-kernel: f[b][c][y][x] fp32 -> fragment-order bf16 rows ----
// fTg[b*64+y] = [kchunk 0..7][xslot 0..65][8 bf16], xslot 0 and 65 are zeros.
__global__ __launch_bounds__(256) void nlwa_pre(const float* __restrict__ f,
                                                uint4* __restrict__ fTg) {
    const int b = blockIdx.x >> 6, y = blockIdx.x & 63;
    const float* fb = f + (size_t)b * CH * NPIX + y * WW;   // + c*4096 + x
    uint4* dst = fTg + (size_t)blockIdx.x * ROWCH;
    for (int idx = threadIdx.x; idx < ROWCH; idx += 256) {
        const int kc = idx / 66, xs = idx - kc * 66;
        uint4 v = {0u, 0u, 0u, 0u};
        if (xs >= 1 && xs <= 64) {
            const int x = xs - 1;
            unsigned h[8];
#pragma unroll
            for (int j = 0; j < 8; ++j) {
                unsigned u = __float_as_uint(fb[(size_t)(kc * 8 + j) * NPIX + x]);
                u = u + 0x7fffu + ((u >> 16) & 1u);   // RNE to bf16
                h[j] = u >> 16;
            }
            v.x = h[0] | (h[1] << 16); v.y = h[2] | (h[3] << 16);
            v.z = h[4] | (h[5] << 16); v.w = h[6] | (h[7] << 16);
        }
        dst[idx] = v;
    }
}

// ---------------- async 16B global->LDS ----------------
__device__ __forceinline__ void gld16(const uint4* g, char* l) {
    __builtin_amdgcn_global_load_lds(
        (const __attribute__((address_space(1))) unsigned int*)g,
        (__attribute__((address_space(3))) unsigned int*)l, 16, 0, 0);
}

// ---------------- main kernel: grid 512 = (b, ny, key-half) ----------------
__global__ __launch_bounds__(256, 2) void nlwa_main(const float* __restrict__ x_lab,
                                                    const uint4* __restrict__ fTg,
                                                    float* __restrict__ pw) {
    // LDS rows: 0-2 Q(dy), 3-6 K slots (rolling by krow&3), 7 zero row. 67584 B.
    __shared__ __align__(16) char smem[8 * ROWB];

    const int tid = threadIdx.x;
    const int bid = blockIdx.x;
    const int b = bid >> 7, ny = (bid >> 1) & 63, half = bid & 1;
    const int my0 = half * 32;
    const int w = tid >> 6, lane = tid & 63;
    const int quad = lane >> 4, nl = lane & 15;
    const int qofs = (w & 1) * 32;       // wave's query offset
    const int kofs = (w >> 1) * 32;      // wave's key offset

    const uint4* fT = fTg + (size_t)b * (64 * ROWCH);

    // ---- init staging: zero row, Q rows, K rows my0-1..my0+1 ----
    {
        const uint4 z = {0u, 0u, 0u, 0u};
        uint4* zr = (uint4*)(smem + 7 * ROWB);
        for (int i = tid; i < ROWCH; i += 256) zr[i] = z;
#pragma unroll
        for (int dyi = 0; dyi < 3; ++dyi) {
            const int qr = ny + dyi - 1;
            uint4* dst = (uint4*)(smem + dyi * ROWB);
            if (qr >= 0 && qr < 64) {
                const uint4* src = fT + (size_t)qr * ROWCH;
                for (int i = tid; i < ROWCH; i += 256) dst[i] = src[i];
            } else {
                for (int i = tid; i < ROWCH; i += 256) dst[i] = z;
            }
        }
        for (int r = my0 - 1; r <= my0 + 1; ++r) {
            if (r >= 0 && r < 64) {
                uint4* dst = (uint4*)(smem + (3 + (r & 3)) * ROWB);
                const uint4* src = fT + (size_t)r * ROWCH;
                for (int i = tid; i < ROWCH; i += 256) dst[i] = src[i];
            }
        }
    }
    __syncthreads();

    // ---- preload 36 A fragments (query side, my-invariant) ----
    bf16x8 AF[36];
    const int laneoff = (quad * 66 + nl) * 16;   // kchunk-lane + x-lane part
    {
#pragma unroll
        for (int d = 0; d < 9; ++d) {
            const int dyi = d / 3, dx = d - dyi * 3;   // dx in {0,1,2} == shift+1
#pragma unroll
            for (int ks = 0; ks < 2; ++ks) {
#pragma unroll
                for (int ti = 0; ti < 2; ++ti) {
                    const int off = dyi * ROWB + laneoff +
                                    (ks * 264 + qofs + ti * 16 + dx) * 16;
                    AF[(d * 2 + ks) * 2 + ti] = *(const bf16x8*)(smem + off);
                }
            }
        }
    }

    // ---- online softmax state: 8 query slots per lane ----
    float m_[8], l_[8], A0[8], A1[8], A2[8];
#pragma unroll
    for (int s = 0; s < 8; ++s) {
        m_[s] = -3.0e38f; l_[s] = 0.0f; A0[s] = 0.0f; A1[s] = 0.0f; A2[s] = 0.0f;
    }

    const float* xl = x_lab + (size_t)b * 3 * NPIX;
    const int kx0 = kofs + nl, kx1 = kofs + 16 + nl;

    for (int my = my0; my < my0 + 32; ++my) {
        // prefetch key row my+2 into slot (my+2)&3 (distance-2 pipeline)
        {
            int pr = my + 2; if (pr > 63) pr = 63;
            const uint4* src = fT + (size_t)pr * ROWCH + w * 132 + lane;
            char* dst = smem + (3 + ((my + 2) & 3)) * ROWB + w * 132 * 16;
            gld16(src, dst);
            gld16(src + 64, dst + 1024);
            if (lane < 4) gld16(src + 128, dst + 2048);
        }
        // x_lab values for this key row (L2-hot scalars)
        const float* xr = xl + my * 64;
        const float xv00 = xr[kx0], xv01 = xr[NPIX + kx0], xv02 = xr[2 * NPIX + kx0];
        const float xv10 = xr[kx1], xv11 = xr[NPIX + kx1], xv12 = xr[2 * NPIX + kx1];

        // key row base pointers (wave-uniform; OOB -> zero row)
        const char* kb[3];
#pragma unroll
        for (int dyi = 0; dyi < 3; ++dyi) {
            const int kr = my + dyi - 1;
            kb[dyi] = (kr >= 0 && kr < 64) ? (smem + (3 + (kr & 3)) * ROWB)
                                           : (smem + 7 * ROWB);
        }

        f32x4 a00 = {0.f, 0.f, 0.f, 0.f}, a01 = a00, a10 = a00, a11 = a00;
#pragma unroll
        for (int d = 0; d < 9; ++d) {
            const char* base = kb[d / 3];
            const int dx = d - (d / 3) * 3;
#pragma unroll
            for (int ks = 0; ks < 2; ++ks) {
                const int uo = (ks * 264 + kofs + dx) * 16;
                const bf16x8 B0 = *(const bf16x8*)(base + laneoff + uo);
                const bf16x8 B1 = *(const bf16x8*)(base + laneoff + uo + 256);
                const int fi = (d * 2 + ks) * 2;
                a00 = __builtin_amdgcn_mfma_f32_16x16x32_bf16(AF[fi + 0], B0, a00, 0, 0, 0);
                a10 = __builtin_amdgcn_mfma_f32_16x16x32_bf16(AF[fi + 1], B0, a10, 0, 0, 0);
                a01 = __builtin_amdgcn_mfma_f32_16x16x32_bf16(AF[fi + 0], B1, a01, 0, 0, 0);
                a11 = __builtin_amdgcn_mfma_f32_16x16x32_bf16(AF[fi + 1], B1, a11, 0, 0, 0);
            }
        }

        // online softmax update (2 keys per query slot)
#pragma unroll
        for (int ti = 0; ti < 2; ++ti) {
#pragma unroll
            for (int r = 0; r < 4; ++r) {
                const int s = ti * 4 + r;
                const float v0 = (ti ? a10[r] : a00[r]) * SCALE;
                const float v1 = (ti ? a11[r] : a01[r]) * SCALE;
                const float mn = fmaxf(m_[s], fmaxf(v0, v1));
                const float sc = __expf(m_[s] - mn);
                const float e0 = __expf(v0 - mn);
                const float e1 = __expf(v1 - mn);
                l_[s] = l_[s] * sc + e0 + e1;
                A0[s] = A0[s] * sc + e0 * xv00 + e1 * xv10;
                A1[s] = A1[s] * sc + e0 * xv01 + e1 * xv11;
                A2[s] = A2[s] * sc + e0 * xv02 + e1 * xv12;
                m_[s] = mn;
            }
        }
        __syncthreads();   // publishes prefetch my+2, guards slot reuse
    }

    // ---- block-level combine: dump 32 partials/query, reduce, write ws ----
    float* scr = (float*)smem;              // [64 q][32 p][5]
    const int p = (w >> 1) * 16 + nl;
#pragma unroll
    for (int s = 0; s < 8; ++s) {
        const int q = qofs + (s >> 2) * 16 + quad * 4 + (s & 3);
        float* o = scr + (q * 32 + p) * 5;
        o[0] = m_[s]; o[1] = l_[s]; o[2] = A0[s]; o[3] = A1[s]; o[4] = A2[s];
    }
    __syncthreads();
    if (tid < 64) {
        const float* basep = scr + tid * 32 * 5;
        float mx = -3.0e38f;
        for (int i = 0; i < 32; ++i) mx = fmaxf(mx, basep[i * 5]);
        float L = 0.f, c0 = 0.f, c1 = 0.f, c2 = 0.f;
        for (int i = 0; i < 32; ++i) {
            const float* pp = basep + i * 5;
            const float wgt = __expf(pp[0] - mx);
            L += wgt * pp[1]; c0 += wgt * pp[2]; c1 += wgt * pp[3]; c2 += wgt * pp[4];
        }
        float* o = pw + (size_t)bid * 512 + tid * 8;
        o[0] = mx; o[1] = L; o[2] = c0; o[3] = c1; o[4] = c2;
    }
}

// ---------------- combine the two key-halves, write output ----------------
__global__ __launch_bounds__(64) void nlwa_combine(const float* __restrict__ pw,
                                                   float* __restrict__ out) {
    const int r = blockIdx.x;       // b*64 + ny
    const int q = threadIdx.x;
    const float* p0 = pw + (size_t)(r * 2) * 512 + q * 8;
    const float* p1 = p0 + 512;
    const float m0 = p0[0], m1 = p1[0];
    const float mx = fmaxf(m0, m1);
    const float w0 = __expf(m0 - mx), w1 = __expf(m1 - mx);
    const float L = w0 * p0[1] + w1 * p1[1];
    const float inv = 1.0f / L;
    const int b = r >> 6, ny = r & 63;
    float* o = out + (size_t)b * 3 * NPIX + ny * 64 + q;
    o[0]        = (w0 * p0[2] + w1 * p1[2]) * inv;
    o[NPIX]     = (w0 * p0[3] + w1 * p1[3]) * inv;
    o[2 * NPIX] = (w0 * p0[4] + w1 * p1[4]) * inv;
}

extern "C" void kernel_launch(void* const* d_in, const int* in_sizes, int n_in,
                              void* d_out, int out_size, void* d_ws, size_t ws_size,
                              hipStream_t stream) {
    (void)in_sizes; (void)n_in; (void)out_size; (void)ws_size;
    const float* x_lab   = (const float*)d_in[0];
    const float* feature = (const float*)d_in[1];
    float* out = (float*)d_out;
    uint4* fTg = (uint4*)d_ws;                                  // 2,162,688 B
    float* pw  = (float*)((char*)d_ws + (size_t)256 * ROWB);    // 1 MB partials
    nlwa_pre<<<dim3(256), dim3(256), 0, stream>>>(feature, fTg);
    nlwa_main<<<dim3(512), dim3(256), 0, stream>>>(x_lab, fTg, pw);
    nlwa_combine<<<dim3(256), dim3(64), 0, stream>>>(pw, out);
}

// Round 3
// 135.531 us; speedup vs baseline: 6.9170x; 1.0213x over previous
//
#include <hip/hip_runtime.h>

// NonlocalWeightedAverage via 9-shift bf16 MFMA flash attention, v2.
// A (query) fragments register-resident from global; K rows stream through a
// 6-slot LDS ring; one 512-thread block per (b,ny) -> no combine kernel.

#define HH 64
#define WW 64
#define CH 64
#define NPIX 4096
#define SCALE 10.0f
#define ROWCH 528              // 16B chunks per padded row: 8 kchunks * 66 xslots
#define ROWB  (ROWCH * 16)     // 8448 bytes

typedef __attribute__((ext_vector_type(8))) short bf16x8;
typedef __attribute__((ext_vector_type(4))) float f32x4;

// ---------------- pre-kernel: f[b][c][y][x] fp32 -> fragment-order bf16 rows ----
// fTg[b*64+y] = [kchunk 0..7][xslot 0..65][8 bf16], xslot 0 and 65 are zeros.
__global__ __launch_bounds__(256) void nlwa_pre(const float* __restrict__ f,
                                                uint4* __restrict__ fTg) {
    const int b = blockIdx.x >> 6, y = blockIdx.x & 63;
    const float* fb = f + (size_t)b * CH * NPIX + y * WW;   // + c*4096 + x
    uint4* dst = fTg + (size_t)blockIdx.x * ROWCH;
    for (int idx = threadIdx.x; idx < ROWCH; idx += 256) {
        const int kc = idx / 66, xs = idx - kc * 66;
        uint4 v = {0u, 0u, 0u, 0u};
        if (xs >= 1 && xs <= 64) {
            const int x = xs - 1;
            unsigned h[8];
#pragma unroll
            for (int j = 0; j < 8; ++j) {
                unsigned u = __float_as_uint(fb[(size_t)(kc * 8 + j) * NPIX + x]);
                u = u + 0x7fffu + ((u >> 16) & 1u);   // RNE to bf16
                h[j] = u >> 16;
            }
            v.x = h[0] | (h[1] << 16); v.y = h[2] | (h[3] << 16);
            v.z = h[4] | (h[5] << 16); v.w = h[6] | (h[7] << 16);
        }
        dst[idx] = v;
    }
}

// ---------------- async 16B global->LDS ----------------
__device__ __forceinline__ void gld16(const uint4* g, char* l) {
    __builtin_amdgcn_global_load_lds(
        (const __attribute__((address_space(1))) unsigned int*)g,
        (__attribute__((address_space(3))) unsigned int*)l, 16, 0, 0);
}

// ---------------- main kernel: grid 256 = (b, ny), 512 threads ----------------
__global__ __launch_bounds__(512, 2) void nlwa_main(const float* __restrict__ x_lab,
                                                    const uint4* __restrict__ fTg,
                                                    float* __restrict__ out) {
    // LDS: slots 0-5 = K-row ring (row % 6), slot 6 = zero row. 59136 B.
    __shared__ __align__(16) char smem[7 * ROWB];

    const int tid = threadIdx.x;
    const int b = blockIdx.x >> 6, ny = blockIdx.x & 63;
    const int w = tid >> 6, lane = tid & 63;
    const int quad = lane >> 4, nl = lane & 15;
    const int qhalf = w & 1, khalf = (w >> 1) & 1, par = w >> 2;
    const int qofs = qhalf * 32, kofs = khalf * 32;

    const uint4* fT = fTg + (size_t)b * (64 * ROWCH);

    // ---- init: zero row + K rows 0,1,2 into ring slots 0,1,2 ----
    {
        const uint4 z = {0u, 0u, 0u, 0u};
        uint4* s6 = (uint4*)(smem + 6 * ROWB);
        for (int i = tid; i < ROWCH; i += 512) s6[i] = z;
#pragma unroll
        for (int r = 0; r < 3; ++r) {
            uint4* dst = (uint4*)(smem + r * ROWB);
            const uint4* src = fT + (size_t)r * ROWCH;
            for (int i = tid; i < ROWCH; i += 512) dst[i] = src[i];
        }
    }

    // ---- A fragments from GLOBAL into registers (my-invariant, no aliasing) ----
    bf16x8 AF[36];
    {
        const bf16x8 zf = {0, 0, 0, 0, 0, 0, 0, 0};
#pragma unroll
        for (int d = 0; d < 9; ++d) {
            const int dyi = d / 3, dx = d - dyi * 3;
            const int qr = ny + dyi - 1;
            const bool ok = (qr >= 0) && (qr < 64);
            const char* rowp = (const char*)(fT + (size_t)(ok ? qr : 0) * ROWCH);
#pragma unroll
            for (int ks = 0; ks < 2; ++ks) {
#pragma unroll
                for (int ti = 0; ti < 2; ++ti) {
                    const int unit = (quad + ks * 4) * 66 + (qofs + ti * 16 + nl + dx);
                    AF[(d * 2 + ks) * 2 + ti] =
                        ok ? *(const bf16x8*)(rowp + unit * 16) : zf;
                }
            }
        }
    }

    // ---- online softmax state: 8 query slots per lane ----
    float m_[8], l_[8], A0[8], A1[8], A2[8];
#pragma unroll
    for (int s = 0; s < 8; ++s) {
        m_[s] = -3.0e38f; l_[s] = 0.0f; A0[s] = 0.0f; A1[s] = 0.0f; A2[s] = 0.0f;
    }

    const float* xl = x_lab + (size_t)b * 3 * NPIX;
    const int kx0 = kofs + nl, kx1 = kofs + 16 + nl;
    const int laneoff = (quad * 66 + nl) * 16;

    __syncthreads();

    for (int my2 = 0; my2 < 64; my2 += 2) {
        const int myw = my2 + par;   // this wave's key row

        // ---- prefetch rows my2+3 (waves 0-3) and my2+4 (waves 4-7) ----
        {
            const int pr = my2 + 3 + par;          // row this wave group loads
            if (pr <= 63) {
                const uint4* src = fT + (size_t)pr * ROWCH;
                char* dst = smem + (pr % 6) * ROWB;
                const int seg = w & 3;             // 4 waves x 2 = 8 segs of 64
#pragma unroll
                for (int j = 0; j < 2; ++j) {
                    const int u = (seg * 2 + j) * 64 + lane;
                    gld16(src + u, dst + u * 16);
                }
                if ((w & 3) == 0 && lane < 16) {   // leftover units 512..527
                    const int u = 512 + lane;
                    gld16(src + u, dst + u * 16);
                }
            }
        }

        // x_lab values for this wave's key row
        const float* xr = xl + myw * 64;
        const float xv00 = xr[kx0], xv01 = xr[NPIX + kx0], xv02 = xr[2 * NPIX + kx0];
        const float xv10 = xr[kx1], xv11 = xr[NPIX + kx1], xv12 = xr[2 * NPIX + kx1];

        // key row base pointers (wave-uniform; OOB -> zero row)
        const char* kb[3];
#pragma unroll
        for (int dyi = 0; dyi < 3; ++dyi) {
            const int kr = myw + dyi - 1;
            kb[dyi] = (kr >= 0 && kr < 64) ? (smem + (kr % 6) * ROWB)
                                           : (smem + 6 * ROWB);
        }

        f32x4 a00 = {0.f, 0.f, 0.f, 0.f}, a01 = a00, a10 = a00, a11 = a00;
#pragma unroll
        for (int d = 0; d < 9; ++d) {
            const char* base = kb[d / 3];
            const int dx = d - (d / 3) * 3;
#pragma unroll
            for (int ks = 0; ks < 2; ++ks) {
                const int uo = (ks * 264 + kofs + dx) * 16;
                const bf16x8 B0 = *(const bf16x8*)(base + laneoff + uo);
                const bf16x8 B1 = *(const bf16x8*)(base + laneoff + uo + 256);
                const int fi = (d * 2 + ks) * 2;
                a00 = __builtin_amdgcn_mfma_f32_16x16x32_bf16(AF[fi + 0], B0, a00, 0, 0, 0);
                a10 = __builtin_amdgcn_mfma_f32_16x16x32_bf16(AF[fi + 1], B0, a10, 0, 0, 0);
                a01 = __builtin_amdgcn_mfma_f32_16x16x32_bf16(AF[fi + 0], B1, a01, 0, 0, 0);
                a11 = __builtin_amdgcn_mfma_f32_16x16x32_bf16(AF[fi + 1], B1, a11, 0, 0, 0);
            }
        }

        // ---- online softmax update (2 keys per query slot) ----
#pragma unroll
        for (int ti = 0; ti < 2; ++ti) {
#pragma unroll
            for (int r = 0; r < 4; ++r) {
                const int s = ti * 4 + r;
                const float v0 = (ti ? a10[r] : a00[r]) * SCALE;
                const float v1 = (ti ? a11[r] : a01[r]) * SCALE;
                const float mn = fmaxf(m_[s], fmaxf(v0, v1));
                const float sc = __expf(m_[s] - mn);
                const float e0 = __expf(v0 - mn);
                const float e1 = __expf(v1 - mn);
                l_[s] = l_[s] * sc + e0 + e1;
                A0[s] = A0[s] * sc + e0 * xv00 + e1 * xv10;
                A1[s] = A1[s] * sc + e0 * xv01 + e1 * xv11;
                A2[s] = A2[s] * sc + e0 * xv02 + e1 * xv12;
                m_[s] = mn;
            }
        }
        __syncthreads();   // publishes prefetch, guards ring slot reuse
    }

    // ---- combine: parity-0 waves dump, parity-1 merge, lane-reduce ----
    float* scr = (float*)smem;              // [64 q][32 p][5] = 40960 B
    const int p = khalf * 16 + nl;
    if (par == 0) {
#pragma unroll
        for (int s = 0; s < 8; ++s) {
            const int q = qofs + (s >> 2) * 16 + quad * 4 + (s & 3);
            float* o = scr + (q * 32 + p) * 5;
            o[0] = m_[s]; o[1] = l_[s]; o[2] = A0[s]; o[3] = A1[s]; o[4] = A2[s];
        }
    }
    __syncthreads();
    if (par == 1) {
#pragma unroll
        for (int s = 0; s < 8; ++s) {
            const int q = qofs + (s >> 2) * 16 + quad * 4 + (s & 3);
            float* o = scr + (q * 32 + p) * 5;
            const float m2 = o[0];
            const float mn = fmaxf(m_[s], m2);
            const float w1 = __expf(m_[s] - mn), w2 = __expf(m2 - mn);
            o[0] = mn;
            o[1] = w1 * l_[s] + w2 * o[1];
            o[2] = w1 * A0[s] + w2 * o[2];
            o[3] = w1 * A1[s] + w2 * o[3];
            o[4] = w1 * A2[s] + w2 * o[4];
        }
    }
    __syncthreads();
    if (tid < 64) {
        const float* basep = scr + tid * 32 * 5;
        float mx = -3.0e38f;
        for (int i = 0; i < 32; ++i) mx = fmaxf(mx, basep[i * 5]);
        float L = 0.f, c0 = 0.f, c1 = 0.f, c2 = 0.f;
        for (int i = 0; i < 32; ++i) {
            const float* pp = basep + i * 5;
            const float wgt = __expf(pp[0] - mx);
            L += wgt * pp[1]; c0 += wgt * pp[2]; c1 += wgt * pp[3]; c2 += wgt * pp[4];
        }
        const float inv = 1.0f / L;
        float* o = out + (size_t)b * 3 * NPIX + ny * 64 + tid;
        o[0]        = c0 * inv;
        o[NPIX]     = c1 * inv;
        o[2 * NPIX] = c2 * inv;
    }
}

extern "C" void kernel_launch(void* const* d_in, const int* in_sizes, int n_in,
                              void* d_out, int out_size, void* d_ws, size_t ws_size,
                              hipStream_t stream) {
    (void)in_sizes; (void)n_in; (void)out_size; (void)ws_size;
    const float* x_lab   = (const float*)d_in[0];
    const float* feature = (const float*)d_in[1];
    float* out = (float*)d_out;
    uint4* fTg = (uint4*)d_ws;                                  // 2,162,688 B
    nlwa_pre<<<dim3(256), dim3(256), 0, stream>>>(feature, fTg);
    nlwa_main<<<dim3(256), dim3(512), 0, stream>>>(x_lab, fTg, out);
}